// Round 1
// baseline (583.451 us; speedup 1.0000x reference)
//
#include <hip/hip_runtime.h>
#include <hip/hip_bf16.h>
#include <math.h>

// Problem constants
#define B_  8
#define S_  1024
#define D_  1024
#define H_  16
#define HD_ 64
#define F_  4096
#define NROWS_ (B_*S_)          // 8192
#define SCALING_ 0.125f         // HD^-0.5
#define EPS_ 1e-5f

typedef __attribute__((ext_vector_type(8))) short bf16x8;   // 8 bf16 in 4 VGPRs (guide §3)
typedef __attribute__((ext_vector_type(4))) float f32x4;
typedef __attribute__((ext_vector_type(4))) unsigned short us4;

// ---------- helpers ----------
__device__ __forceinline__ unsigned short f2bf(float f) {
    union { float f; unsigned int u; } x; x.f = f;
    unsigned int u = x.u;
    u += 0x7FFFu + ((u >> 16) & 1u);          // round-to-nearest-even
    return (unsigned short)(u >> 16);
}

__device__ __forceinline__ f32x4 mfma16(bf16x8 a, bf16x8 b, f32x4 c) {
    return __builtin_amdgcn_mfma_f32_16x16x32_bf16(a, b, c, 0, 0, 0);
}

// async global->LDS, 16B per lane.  LDS dest must be WAVE-UNIFORM base
// (HW scatters lane i at base + i*16); global src is per-lane.
__device__ __forceinline__ void async_copy16(const unsigned short* g, unsigned short* l) {
    __builtin_amdgcn_global_load_lds(
        (const __attribute__((address_space(1))) void*)g,
        (__attribute__((address_space(3))) void*)l,
        16, 0, 0);
}

// swizzled LDS fragment load: tiles are [rows][64] bf16, 16B-granule XOR swizzle
// granule' = granule ^ (row&7)  (128B rows -> 8 granules -> full 3-bit XOR, ~2-way free)
__device__ __forceinline__ bf16x8 ld_swz(const unsigned short* lds, int row, int k) {
    const int kg = (k >> 3) ^ (row & 7);
    return *reinterpret_cast<const bf16x8*>(lds + row * 64 + kg * 8);
}

// ---------- fp32 -> bf16 convert ----------
__global__ __launch_bounds__(256)
void cvt_kernel(const float* __restrict__ in, unsigned short* __restrict__ out, int n4) {
    int i = blockIdx.x * 256 + threadIdx.x;
    if (i >= n4) return;
    const float4 v = reinterpret_cast<const float4*>(in)[i];
    us4 o = { f2bf(v.x), f2bf(v.y), f2bf(v.z), f2bf(v.w) };
    reinterpret_cast<us4*>(out)[i] = o;
}

// ---------- GEMM C = A(MxK) * B(NxK)^T, bf16 in, fp32 acc ----------
// 128x128 tile, BK=64, 256 threads (2x2 waves of 64x64), 16x16x32 MFMA.
// MODE 0: out bf16 -> [B,H,S,HD] (q/k layout), val=(acc+bias)*scale
// MODE 1: out bf16 -> [B,H,HD,S] (v transposed layout)
// MODE 2: out f32  -> acc+bias+resid (row-major MxN)
// MODE 3: out bf16 -> gelu_exact(acc+bias) (row-major MxN)
// MODE 4: same as 2
template<int MODE>
__global__ __launch_bounds__(256)
void gemm_bt(const unsigned short* __restrict__ A,
             const unsigned short* __restrict__ Bw,
             const float* __restrict__ bias,
             const float* __restrict__ resid,
             float* __restrict__ outf,
             unsigned short* __restrict__ outb,
             float scale, int M, int N, int K)
{
    alignas(16) __shared__ unsigned short lA[128 * 64];
    alignas(16) __shared__ unsigned short lB[128 * 64];
    const int tid  = threadIdx.x;
    const int lane = tid & 63, wave = tid >> 6;
    const int wr = wave >> 1, wc = wave & 1;
    const int l15 = lane & 15, lg = lane >> 4;
    const int brow = blockIdx.y * 128, bcol = blockIdx.x * 128;

    f32x4 acc[4][4];
#pragma unroll
    for (int m = 0; m < 4; ++m)
#pragma unroll
        for (int n = 0; n < 4; ++n) acc[m][n] = f32x4{0.f, 0.f, 0.f, 0.f};

    for (int k0 = 0; k0 < K; k0 += 64) {
        // stage 128x64 bf16 tiles of A and B (16KB each), linear LDS dest,
        // inverse-swizzled global source (rule #21)
#pragma unroll
        for (int j = 0; j < 4; ++j) {
            const int c   = wave * 4 + j;       // 1KB chunk id 0..15
            const int p   = c * 64 + lane;      // 16B granule 0..1023
            const int row = p >> 3;
            const int kg  = (p & 7) ^ (row & 7);
            async_copy16(&A [(size_t)(brow + row) * K + k0 + kg * 8], &lA[c * 512]);
            async_copy16(&Bw[(size_t)(bcol + row) * K + k0 + kg * 8], &lB[c * 512]);
        }
        __syncthreads();
#pragma unroll
        for (int kk = 0; kk < 2; ++kk) {
            bf16x8 af[4], bfr[4];
#pragma unroll
            for (int m = 0; m < 4; ++m) af[m]  = ld_swz(lA, wr * 64 + m * 16 + l15, kk * 32 + lg * 8);
#pragma unroll
            for (int n = 0; n < 4; ++n) bfr[n] = ld_swz(lB, wc * 64 + n * 16 + l15, kk * 32 + lg * 8);
#pragma unroll
            for (int m = 0; m < 4; ++m)
#pragma unroll
                for (int n = 0; n < 4; ++n)
                    acc[m][n] = mfma16(af[m], bfr[n], acc[m][n]);
        }
        __syncthreads();
    }

    // epilogue.  C/D layout: col = lane&15, row = (lane>>4)*4 + r  (guide §3, m89-verified)
#pragma unroll
    for (int m = 0; m < 4; ++m) {
#pragma unroll
        for (int n = 0; n < 4; ++n) {
#pragma unroll
            for (int r = 0; r < 4; ++r) {
                const int grow = brow + wr * 64 + m * 16 + lg * 4 + r;
                const int gcol = bcol + wc * 64 + n * 16 + l15;
                float v = acc[m][n][r] + bias[gcol];
                if constexpr (MODE == 0) {
                    v *= scale;
                    const int b = grow >> 10, s = grow & 1023, h = gcol >> 6, hd = gcol & 63;
                    outb[(((size_t)b * H_ + h) * S_ + s) * HD_ + hd] = f2bf(v);
                } else if constexpr (MODE == 1) {
                    const int b = grow >> 10, s = grow & 1023, h = gcol >> 6, hd = gcol & 63;
                    outb[(((size_t)b * H_ + h) * HD_ + hd) * S_ + s] = f2bf(v);
                } else if constexpr (MODE == 2 || MODE == 4) {
                    outf[(size_t)grow * N + gcol] = v + resid[(size_t)grow * N + gcol];
                } else { // MODE 3: exact GELU
                    float g = 0.5f * v * (1.0f + erff(v * 0.70710678118654752f));
                    outb[(size_t)grow * N + gcol] = f2bf(g);
                }
            }
        }
    }
}

// ---------- flash attention ----------
// grid (B*H, S/64).  256 threads = 4 waves, each wave owns 16 query rows.
// q,k: [B,H,S,64] bf16 (q pre-scaled).  vt: [B,H,64,S] bf16 (V transposed).
// out: attn [B,S,D] bf16.
__global__ __launch_bounds__(256)
void attn_kernel(const unsigned short* __restrict__ qb,
                 const unsigned short* __restrict__ kb,
                 const unsigned short* __restrict__ vtb,
                 unsigned short* __restrict__ attn)
{
    alignas(16) __shared__ unsigned short lK[64 * 64];
    alignas(16) __shared__ unsigned short lV[64 * 64];
    alignas(16) __shared__ unsigned short lP[4][16 * 72];  // per-wave P tile, +8 pad
    const int bh = blockIdx.x, qblk = blockIdx.y;
    const int tid = threadIdx.x, lane = tid & 63, wave = tid >> 6;
    const int l15 = lane & 15, lg = lane >> 4;
    const int b = bh >> 4, h = bh & 15;

    const unsigned short* Kg = kb  + (size_t)bh * S_ * HD_;
    const unsigned short* Vg = vtb + (size_t)bh * HD_ * S_;
    const unsigned short* Qg = qb  + ((size_t)bh * S_ + qblk * 64 + wave * 16) * HD_;

    // Q fragment: A-layout row=lane&15, k=(lane>>4)*8 (+32)
    bf16x8 qf0 = *reinterpret_cast<const bf16x8*>(Qg + l15 * HD_ + lg * 8);
    bf16x8 qf1 = *reinterpret_cast<const bf16x8*>(Qg + l15 * HD_ + lg * 8 + 32);

    float mr[4], lr[4];
    f32x4 o[4];
#pragma unroll
    for (int r = 0; r < 4; ++r) { mr[r] = -1e30f; lr[r] = 0.f; }
#pragma unroll
    for (int n = 0; n < 4; ++n) o[n] = f32x4{0.f, 0.f, 0.f, 0.f};

    for (int t = 0; t < 16; ++t) {
        // stage K tile [64 key][64 d] and Vt tile [64 d][64 key], swizzled
#pragma unroll
        for (int j = 0; j < 2; ++j) {
            const int c   = wave * 2 + j;       // 0..7
            const int p   = c * 64 + lane;      // granule 0..511
            const int row = p >> 3;
            const int kg  = (p & 7) ^ (row & 7);
            async_copy16(&Kg[(size_t)(t * 64 + row) * HD_ + kg * 8], &lK[c * 512]);
            async_copy16(&Vg[(size_t)row * S_ + t * 64 + kg * 8],    &lV[c * 512]);
        }
        __syncthreads();

        // S = Q K^T : D row = query (lg*4+r), col = key (n*16+l15)
        f32x4 sf[4];
#pragma unroll
        for (int n = 0; n < 4; ++n) {
            f32x4 z = {0.f, 0.f, 0.f, 0.f};
            z     = mfma16(qf0, ld_swz(lK, n * 16 + l15, lg * 8), z);
            sf[n] = mfma16(qf1, ld_swz(lK, n * 16 + l15, 32 + lg * 8), z);
        }

        // online softmax (row = query lives across 16-lane group, butterfly reduce)
        float tmax[4], corr[4], psum[4];
#pragma unroll
        for (int r = 0; r < 4; ++r)
            tmax[r] = fmaxf(fmaxf(sf[0][r], sf[1][r]), fmaxf(sf[2][r], sf[3][r]));
#pragma unroll
        for (int off = 1; off < 16; off <<= 1)
#pragma unroll
            for (int r = 0; r < 4; ++r) tmax[r] = fmaxf(tmax[r], __shfl_xor(tmax[r], off, 64));
#pragma unroll
        for (int r = 0; r < 4; ++r) {
            float mnew = fmaxf(mr[r], tmax[r]);
            corr[r] = __expf(mr[r] - mnew);
            mr[r] = mnew;
            psum[r] = 0.f;
        }
        unsigned short pbf[4][4];
#pragma unroll
        for (int n = 0; n < 4; ++n)
#pragma unroll
            for (int r = 0; r < 4; ++r) {
                float p = __expf(sf[n][r] - mr[r]);
                psum[r] += p;
                pbf[n][r] = f2bf(p);
            }
#pragma unroll
        for (int off = 1; off < 16; off <<= 1)
#pragma unroll
            for (int r = 0; r < 4; ++r) psum[r] += __shfl_xor(psum[r], off, 64);
#pragma unroll
        for (int r = 0; r < 4; ++r) lr[r] = lr[r] * corr[r] + psum[r];
#pragma unroll
        for (int n = 0; n < 4; ++n)
#pragma unroll
            for (int r = 0; r < 4; ++r) o[n][r] *= corr[r];

        // P (D-layout) -> LDS -> A-layout fragments, per-wave private tile
        unsigned short* Pl = &lP[wave][0];
#pragma unroll
        for (int n = 0; n < 4; ++n)
#pragma unroll
            for (int r = 0; r < 4; ++r)
                Pl[(lg * 4 + r) * 72 + n * 16 + l15] = pbf[n][r];
        asm volatile("s_waitcnt lgkmcnt(0)" ::: "memory");   // intra-wave cross-lane via LDS
        __builtin_amdgcn_sched_barrier(0);

        // O += P * V : A = P[q][key], B = Vt rows (col=d, k=key)
#pragma unroll
        for (int kk = 0; kk < 2; ++kk) {
            bf16x8 pf = *reinterpret_cast<const bf16x8*>(Pl + l15 * 72 + kk * 32 + lg * 8);
#pragma unroll
            for (int n = 0; n < 4; ++n)
                o[n] = mfma16(pf, ld_swz(lV, n * 16 + l15, kk * 32 + lg * 8), o[n]);
        }
        __syncthreads();
    }

    // write attn[b, s, h*64+d] bf16
#pragma unroll
    for (int n = 0; n < 4; ++n)
#pragma unroll
        for (int r = 0; r < 4; ++r) {
            const int s = qblk * 64 + wave * 16 + lg * 4 + r;
            const int d = h * HD_ + n * 16 + l15;
            attn[((size_t)b * S_ + s) * D_ + d] = f2bf(o[n][r] / lr[r]);
        }
}

// ---------- row LayerNorm over D=1024, one block per row ----------
__global__ __launch_bounds__(256)
void ln_kernel(const float* __restrict__ in, const float* __restrict__ gam,
               const float* __restrict__ bet,
               float* __restrict__ outf, unsigned short* __restrict__ outbf)
{
    const int row = blockIdx.x, t = threadIdx.x;
    const float4 v = reinterpret_cast<const float4*>(in + (size_t)row * D_)[t];
    float s  = v.x + v.y + v.z + v.w;
    float s2 = v.x * v.x + v.y * v.y + v.z * v.z + v.w * v.w;
#pragma unroll
    for (int off = 32; off > 0; off >>= 1) {
        s  += __shfl_down(s, off, 64);
        s2 += __shfl_down(s2, off, 64);
    }
    __shared__ float red[2][4];
    if ((t & 63) == 0) { red[0][t >> 6] = s; red[1][t >> 6] = s2; }
    __syncthreads();
    s  = red[0][0] + red[0][1] + red[0][2] + red[0][3];
    s2 = red[1][0] + red[1][1] + red[1][2] + red[1][3];
    const float mean = s * (1.0f / D_);
    const float rstd = rsqrtf(s2 * (1.0f / D_) - mean * mean + EPS_);
    const float4 g4 = reinterpret_cast<const float4*>(gam)[t];
    const float4 b4 = reinterpret_cast<const float4*>(bet)[t];
    float4 y;
    y.x = (v.x - mean) * rstd * g4.x + b4.x;
    y.y = (v.y - mean) * rstd * g4.y + b4.y;
    y.z = (v.z - mean) * rstd * g4.z + b4.z;
    y.w = (v.w - mean) * rstd * g4.w + b4.w;
    if (outf)  reinterpret_cast<float4*>(outf + (size_t)row * D_)[t] = y;
    if (outbf) {
        us4 o = { f2bf(y.x), f2bf(y.y), f2bf(y.z), f2bf(y.w) };
        reinterpret_cast<us4*>(outbf + (size_t)row * D_)[t] = o;
    }
}

// ---------- launcher ----------
extern "C" void kernel_launch(void* const* d_in, const int* in_sizes, int n_in,
                              void* d_out, int out_size, void* d_ws, size_t ws_size,
                              hipStream_t stream)
{
    const float* hs   = (const float*)d_in[0];
    const float* wq   = (const float*)d_in[1];
    const float* bq   = (const float*)d_in[2];
    const float* wk   = (const float*)d_in[3];
    const float* bk   = (const float*)d_in[4];
    const float* wv   = (const float*)d_in[5];
    const float* bv   = (const float*)d_in[6];
    const float* wo   = (const float*)d_in[7];
    const float* bo   = (const float*)d_in[8];
    const float* ln1g = (const float*)d_in[9];
    const float* ln1b = (const float*)d_in[10];
    const float* fc1w = (const float*)d_in[11];
    const float* fc1b = (const float*)d_in[12];
    const float* fc2w = (const float*)d_in[13];
    const float* fc2b = (const float*)d_in[14];
    const float* ln2g = (const float*)d_in[15];
    const float* ln2b = (const float*)d_in[16];
    float* out = (float*)d_out;

    char* ws = (char*)d_ws;
    const size_t MB = 1024 * 1024;
    // liveness-packed layout, peak 184 MB
    unsigned short* hs_bf = (unsigned short*)(ws + 0);        // 16 MB
    unsigned short* wq_bf = (unsigned short*)(ws + 16 * MB);  //  2 MB
    unsigned short* wk_bf = (unsigned short*)(ws + 18 * MB);
    unsigned short* wv_bf = (unsigned short*)(ws + 20 * MB);
    unsigned short* wo_bf = (unsigned short*)(ws + 22 * MB);
    unsigned short* f1_bf = (unsigned short*)(ws + 24 * MB);  //  8 MB
    unsigned short* f2_bf = (unsigned short*)(ws + 32 * MB);  //  8 MB
    unsigned short* qbf   = (unsigned short*)(ws + 40 * MB);  // 16 MB
    unsigned short* kbf   = (unsigned short*)(ws + 56 * MB);  // 16 MB
    unsigned short* vtbf  = (unsigned short*)(ws + 72 * MB);  // 16 MB
    unsigned short* attnb = (unsigned short*)(ws + 88 * MB);  // 16 MB
    float*          tmp   = (float*)(ws + 104 * MB);          // 32 MB (reused)
    float*          ln1f  = (float*)(ws + 136 * MB);          // 32 MB
    unsigned short* ln1bf = (unsigned short*)(ws + 168 * MB); // 16 MB
    unsigned short* h_bf  = (unsigned short*)(ws + 40 * MB);  // 64 MB, aliases q/k/vt/attn (dead)

    // fp32 -> bf16 casts
    cvt_kernel<<<8192, 256, 0, stream>>>(hs,   hs_bf, 2097152);
    cvt_kernel<<<1024, 256, 0, stream>>>(wq,   wq_bf,  262144);
    cvt_kernel<<<1024, 256, 0, stream>>>(wk,   wk_bf,  262144);
    cvt_kernel<<<1024, 256, 0, stream>>>(wv,   wv_bf,  262144);
    cvt_kernel<<<1024, 256, 0, stream>>>(wo,   wo_bf,  262144);
    cvt_kernel<<<4096, 256, 0, stream>>>(fc1w, f1_bf, 1048576);
    cvt_kernel<<<4096, 256, 0, stream>>>(fc2w, f2_bf, 1048576);

    // projections
    gemm_bt<0><<<dim3(8, 64),  256, 0, stream>>>(hs_bf, wq_bf, bq, nullptr, nullptr, qbf,  SCALING_, NROWS_, D_, D_);
    gemm_bt<0><<<dim3(8, 64),  256, 0, stream>>>(hs_bf, wk_bf, bk, nullptr, nullptr, kbf,  1.0f,     NROWS_, D_, D_);
    gemm_bt<1><<<dim3(8, 64),  256, 0, stream>>>(hs_bf, wv_bf, bv, nullptr, nullptr, vtbf, 1.0f,     NROWS_, D_, D_);
    // attention
    attn_kernel<<<dim3(B_ * H_, S_ / 64), 256, 0, stream>>>(qbf, kbf, vtbf, attnb);
    // out-proj + residual
    gemm_bt<2><<<dim3(8, 64),  256, 0, stream>>>(attnb, wo_bf, bo, hs, tmp, nullptr, 1.0f, NROWS_, D_, D_);
    ln_kernel<<<NROWS_, 256, 0, stream>>>(tmp, ln1g, ln1b, ln1f, ln1bf);
    // FFN
    gemm_bt<3><<<dim3(32, 64), 256, 0, stream>>>(ln1bf, f1_bf, fc1b, nullptr, nullptr, h_bf, 1.0f, NROWS_, F_, D_);
    gemm_bt<4><<<dim3(8, 64),  256, 0, stream>>>(h_bf, f2_bf, fc2b, ln1f, tmp, nullptr, 1.0f, NROWS_, D_, F_);
    ln_kernel<<<NROWS_, 256, 0, stream>>>(tmp, ln2g, ln2b, out, nullptr);
    (void)in_sizes; (void)n_in; (void)out_size; (void)ws_size;
}

// Round 6
// 565.627 us; speedup vs baseline: 1.0315x; 1.0315x over previous
//
#include <hip/hip_runtime.h>
#include <hip/hip_bf16.h>
#include <math.h>

// Problem constants
#define B_  8
#define S_  1024
#define D_  1024
#define H_  16
#define HD_ 64
#define F_  4096
#define NROWS_ (B_*S_)          // 8192
#define SCALING_ 0.125f         // HD^-0.5
#define EPS_ 1e-5f

typedef __attribute__((ext_vector_type(8))) short bf16x8;   // 8 bf16 in 4 VGPRs (guide §3)
typedef __attribute__((ext_vector_type(4))) float f32x4;
typedef __attribute__((ext_vector_type(4))) unsigned short us4;

// ---------- helpers ----------
__device__ __forceinline__ unsigned short f2bf(float f) {
    union { float f; unsigned int u; } x; x.f = f;
    unsigned int u = x.u;
    u += 0x7FFFu + ((u >> 16) & 1u);          // round-to-nearest-even
    return (unsigned short)(u >> 16);
}

__device__ __forceinline__ unsigned int pack_bf2(float a, float b) {
    __hip_bfloat162 h = __float22bfloat162_rn(make_float2(a, b));  // v_cvt_pk_bf16_f32
    union { __hip_bfloat162 h; unsigned int u; } c; c.h = h; return c.u;
}

__device__ __forceinline__ f32x4 mfma16(bf16x8 a, bf16x8 b, f32x4 c) {
    return __builtin_amdgcn_mfma_f32_16x16x32_bf16(a, b, c, 0, 0, 0);
}

// async global->LDS, 16B per lane.  LDS dest must be WAVE-UNIFORM base
// (HW scatters lane i at base + i*16); global src is per-lane.
__device__ __forceinline__ void async_copy16(const unsigned short* g, unsigned short* l) {
    __builtin_amdgcn_global_load_lds(
        (const __attribute__((address_space(1))) void*)g,
        (__attribute__((address_space(3))) void*)l,
        16, 0, 0);
}

// swizzled LDS fragment load: tiles are [rows][64] bf16, 16B-granule XOR swizzle
// granule' = granule ^ (row&7)  (128B rows -> 8 granules -> full 3-bit XOR)
__device__ __forceinline__ bf16x8 ld_swz(const unsigned short* lds, int row, int k) {
    const int kg = (k >> 3) ^ (row & 7);
    return *reinterpret_cast<const bf16x8*>(lds + row * 64 + kg * 8);
}

// ---------- fp32 -> bf16 convert ----------
__global__ __launch_bounds__(256)
void cvt_kernel(const float* __restrict__ in, unsigned short* __restrict__ out, int n4) {
    int i = blockIdx.x * 256 + threadIdx.x;
    if (i >= n4) return;
    const float4 v = reinterpret_cast<const float4*>(in)[i];
    us4 o = { f2bf(v.x), f2bf(v.y), f2bf(v.z), f2bf(v.w) };
    reinterpret_cast<us4*>(out)[i] = o;
}

// ---------- GEMM C = A(MxK) * B(NxK)^T, bf16 in, fp32 acc ----------
// 128x128 tile, BK=64, 256 threads (2x2 waves of 64x64), 16x16x32 MFMA.
// MODE 0: out bf16 -> [B,H,S,HD] (q/k layout), val=(acc+bias)*scale
// MODE 1: out bf16 -> [B,H,HD,S] (v transposed layout)
// MODE 2: out f32  -> acc+bias+resid (row-major MxN)
// MODE 3: out bf16 -> gelu_exact(acc+bias) (row-major MxN)
// MODE 4: same as 2
template<int MODE>
__global__ __launch_bounds__(256)
void gemm_bt(const unsigned short* __restrict__ A,
             const unsigned short* __restrict__ Bw,
             const float* __restrict__ bias,
             const float* __restrict__ resid,
             float* __restrict__ outf,
             unsigned short* __restrict__ outb,
             float scale, int M, int N, int K)
{
    alignas(16) __shared__ unsigned short lA[128 * 64];
    alignas(16) __shared__ unsigned short lB[128 * 64];
    const int tid  = threadIdx.x;
    const int lane = tid & 63, wave = tid >> 6;
    const int wr = wave >> 1, wc = wave & 1;
    const int l15 = lane & 15, lg = lane >> 4;
    const int brow = blockIdx.y * 128, bcol = blockIdx.x * 128;

    f32x4 acc[4][4];
#pragma unroll
    for (int m = 0; m < 4; ++m)
#pragma unroll
        for (int n = 0; n < 4; ++n) acc[m][n] = f32x4{0.f, 0.f, 0.f, 0.f};

    for (int k0 = 0; k0 < K; k0 += 64) {
        // stage 128x64 bf16 tiles of A and B (16KB each), linear LDS dest,
        // inverse-swizzled global source (rule #21)
#pragma unroll
        for (int j = 0; j < 4; ++j) {
            const int c   = wave * 4 + j;       // 1KB chunk id 0..15
            const int p   = c * 64 + lane;      // 16B granule 0..1023
            const int row = p >> 3;
            const int kg  = (p & 7) ^ (row & 7);
            async_copy16(&A [(size_t)(brow + row) * K + k0 + kg * 8], &lA[c * 512]);
            async_copy16(&Bw[(size_t)(bcol + row) * K + k0 + kg * 8], &lB[c * 512]);
        }
        __syncthreads();
#pragma unroll
        for (int kk = 0; kk < 2; ++kk) {
            bf16x8 af[4], bfr[4];
#pragma unroll
            for (int m = 0; m < 4; ++m) af[m]  = ld_swz(lA, wr * 64 + m * 16 + l15, kk * 32 + lg * 8);
#pragma unroll
            for (int n = 0; n < 4; ++n) bfr[n] = ld_swz(lB, wc * 64 + n * 16 + l15, kk * 32 + lg * 8);
#pragma unroll
            for (int m = 0; m < 4; ++m)
#pragma unroll
                for (int n = 0; n < 4; ++n)
                    acc[m][n] = mfma16(af[m], bfr[n], acc[m][n]);
        }
        __syncthreads();
    }

    // epilogue.  C/D layout: col = lane&15, row = (lane>>4)*4 + r  (guide §3, m89-verified)
#pragma unroll
    for (int m = 0; m < 4; ++m) {
#pragma unroll
        for (int n = 0; n < 4; ++n) {
#pragma unroll
            for (int r = 0; r < 4; ++r) {
                const int grow = brow + wr * 64 + m * 16 + lg * 4 + r;
                const int gcol = bcol + wc * 64 + n * 16 + l15;
                float v = acc[m][n][r] + bias[gcol];
                if constexpr (MODE == 0) {
                    v *= scale;
                    const int b = grow >> 10, s = grow & 1023, h = gcol >> 6, hd = gcol & 63;
                    outb[(((size_t)b * H_ + h) * S_ + s) * HD_ + hd] = f2bf(v);
                } else if constexpr (MODE == 1) {
                    const int b = grow >> 10, s = grow & 1023, h = gcol >> 6, hd = gcol & 63;
                    outb[(((size_t)b * H_ + h) * HD_ + hd) * S_ + s] = f2bf(v);
                } else if constexpr (MODE == 2 || MODE == 4) {
                    outf[(size_t)grow * N + gcol] = v + resid[(size_t)grow * N + gcol];
                } else { // MODE 3: exact GELU
                    float g = 0.5f * v * (1.0f + erff(v * 0.70710678118654752f));
                    outb[(size_t)grow * N + gcol] = f2bf(g);
                }
            }
        }
    }
}

// ---------- flash attention (swapped-operand, R2) ----------
// grid (B*H, S/64).  256 threads = 4 waves, each wave owns 16 query rows.
// Computes S^T = mfma(K,Q) so each lane holds 16 scores for ONE query
// (lane-local softmax), and O^T = mfma(V^T, P^T).
// q,k: [B,H,S,64] bf16 (q pre-scaled).  vt: [B,H,64,S] bf16.
// out: attn [B,S,D] bf16.
__global__ __launch_bounds__(256)
void attn_kernel(const unsigned short* __restrict__ qb,
                 const unsigned short* __restrict__ kb,
                 const unsigned short* __restrict__ vtb,
                 unsigned short* __restrict__ attn)
{
    alignas(16) __shared__ unsigned short lK[2][64 * 64];   // dbuf K tile [key][d]
    alignas(16) __shared__ unsigned short lV[2][64 * 64];   // dbuf Vt tile [d][key]
    alignas(16) __shared__ unsigned short lP[4][16 * 72];   // per-wave P[query][key], +8 pad
    const int bh = blockIdx.x, qblk = blockIdx.y;
    const int tid = threadIdx.x, lane = tid & 63, wave = tid >> 6;
    const int l15 = lane & 15, lg = lane >> 4;
    const int b = bh >> 4, h = bh & 15;

    const unsigned short* Kg = kb  + (size_t)bh * S_ * HD_;
    const unsigned short* Vg = vtb + (size_t)bh * HD_ * S_;
    const unsigned short* Qg = qb  + ((size_t)bh * S_ + qblk * 64 + wave * 16) * HD_;

    // Q fragment as MFMA B-operand: col=query=l15, k=d=lg*8 (+32)
    bf16x8 qf0 = *reinterpret_cast<const bf16x8*>(Qg + l15 * HD_ + lg * 8);
    bf16x8 qf1 = *reinterpret_cast<const bf16x8*>(Qg + l15 * HD_ + lg * 8 + 32);

    float mr = -1e30f, lr = 0.f;     // lane-local: running max/denominator for query l15
    f32x4 o[4];                      // O^T fragments: d = m*16+lg*4+r, query = l15
#pragma unroll
    for (int m = 0; m < 4; ++m) o[m] = f32x4{0.f, 0.f, 0.f, 0.f};

    // staging helper (inlined twice): tile t -> buffer buf
#define STAGE(buf, t)                                                              \
    {                                                                              \
        _Pragma("unroll")                                                          \
        for (int j = 0; j < 2; ++j) {                                              \
            const int c   = wave * 2 + j;       /* 1KB chunk 0..7 */               \
            const int p   = c * 64 + lane;      /* 16B granule 0..511 */           \
            const int row = p >> 3;                                                \
            const int kg  = (p & 7) ^ (row & 7);                                   \
            async_copy16(&Kg[(size_t)((t) * 64 + row) * HD_ + kg * 8], &lK[buf][c * 512]); \
            async_copy16(&Vg[(size_t)row * S_ + (t) * 64 + kg * 8],    &lV[buf][c * 512]); \
        }                                                                          \
    }

    STAGE(0, 0);                      // prologue prefetch

    unsigned short* Pl = &lP[wave][0];

    for (int t = 0; t < 16; ++t) {
        const int cur = t & 1;
        __syncthreads();              // drains vmcnt(0): tile t landed; all waves left buf cur^1
        if (t < 15) STAGE(cur ^ 1, t + 1);   // prefetch flies under compute(t)

        // S^T = K Q^T : fragment n -> key = n*16 + lg*4 + r, query = l15
        f32x4 sf[4];
#pragma unroll
        for (int n = 0; n < 4; ++n) {
            f32x4 z = {0.f, 0.f, 0.f, 0.f};
            z     = mfma16(ld_swz(lK[cur], n * 16 + l15, lg * 8),      qf0, z);
            sf[n] = mfma16(ld_swz(lK[cur], n * 16 + l15, 32 + lg * 8), qf1, z);
        }

        // lane-local online softmax (16 in-lane keys + 2 butterfly rounds over lane-groups)
        float tmax = sf[0][0];
#pragma unroll
        for (int n = 0; n < 4; ++n)
#pragma unroll
            for (int r = 0; r < 4; ++r) tmax = fmaxf(tmax, sf[n][r]);
        tmax = fmaxf(tmax, __shfl_xor(tmax, 16, 64));
        tmax = fmaxf(tmax, __shfl_xor(tmax, 32, 64));
        const float mnew = fmaxf(mr, tmax);
        const float corr = __expf(mr - mnew);
        mr = mnew;

        float ps = 0.f;
        uint2 pk[4];                  // packed bf16 P: keys n*16+lg*4+{0..3}, query l15
#pragma unroll
        for (int n = 0; n < 4; ++n) {
            float p0 = __expf(sf[n][0] - mr);
            float p1 = __expf(sf[n][1] - mr);
            float p2 = __expf(sf[n][2] - mr);
            float p3 = __expf(sf[n][3] - mr);
            ps += (p0 + p1) + (p2 + p3);
            pk[n].x = pack_bf2(p0, p1);
            pk[n].y = pack_bf2(p2, p3);
        }
        ps += __shfl_xor(ps, 16, 64);
        ps += __shfl_xor(ps, 32, 64);
        lr = lr * corr + ps;
#pragma unroll
        for (int m = 0; m < 4; ++m)
#pragma unroll
            for (int r = 0; r < 4; ++r) o[m][r] *= corr;

        // P (transposed to [query][key]) -> per-wave LDS tile, 4x ds_write_b64
#pragma unroll
        for (int n = 0; n < 4; ++n)
            *reinterpret_cast<uint2*>(Pl + l15 * 72 + n * 16 + lg * 4) = pk[n];

        // O^T += V^T * P^T : A = Vt rows (d), B = P^T (col=query, k=key)
#pragma unroll
        for (int kk = 0; kk < 2; ++kk) {
            bf16x8 pf = *reinterpret_cast<const bf16x8*>(Pl + l15 * 72 + kk * 32 + lg * 8);
#pragma unroll
            for (int m = 0; m < 4; ++m)
                o[m] = mfma16(ld_swz(lV[cur], m * 16 + l15, kk * 32 + lg * 8), pf, o[m]);
        }
    }
#undef STAGE

    // write attn[b, s=query, h*64 + d], 8B packed stores (4 consecutive d)
    const int s = qblk * 64 + wave * 16 + l15;
    const float rinv = 1.0f / lr;
#pragma unroll
    for (int m = 0; m < 4; ++m) {
        us4 w = { f2bf(o[m][0] * rinv), f2bf(o[m][1] * rinv),
                  f2bf(o[m][2] * rinv), f2bf(o[m][3] * rinv) };
        *reinterpret_cast<us4*>(attn + ((size_t)b * S_ + s) * D_ + h * HD_ + m * 16 + lg * 4) = w;
    }
}

// ---------- row LayerNorm over D=1024, one block per row ----------
__global__ __launch_bounds__(256)
void ln_kernel(const float* __restrict__ in, const float* __restrict__ gam,
               const float* __restrict__ bet,
               float* __restrict__ outf, unsigned short* __restrict__ outbf)
{
    const int row = blockIdx.x, t = threadIdx.x;
    const float4 v = reinterpret_cast<const float4*>(in + (size_t)row * D_)[t];
    float s  = v.x + v.y + v.z + v.w;
    float s2 = v.x * v.x + v.y * v.y + v.z * v.z + v.w * v.w;
#pragma unroll
    for (int off = 32; off > 0; off >>= 1) {
        s  += __shfl_down(s, off, 64);
        s2 += __shfl_down(s2, off, 64);
    }
    __shared__ float red[2][4];
    if ((t & 63) == 0) { red[0][t >> 6] = s; red[1][t >> 6] = s2; }
    __syncthreads();
    s  = red[0][0] + red[0][1] + red[0][2] + red[0][3];
    s2 = red[1][0] + red[1][1] + red[1][2] + red[1][3];
    const float mean = s * (1.0f / D_);
    const float rstd = rsqrtf(s2 * (1.0f / D_) - mean * mean + EPS_);
    const float4 g4 = reinterpret_cast<const float4*>(gam)[t];
    const float4 b4 = reinterpret_cast<const float4*>(bet)[t];
    float4 y;
    y.x = (v.x - mean) * rstd * g4.x + b4.x;
    y.y = (v.y - mean) * rstd * g4.y + b4.y;
    y.z = (v.z - mean) * rstd * g4.z + b4.z;
    y.w = (v.w - mean) * rstd * g4.w + b4.w;
    if (outf)  reinterpret_cast<float4*>(outf + (size_t)row * D_)[t] = y;
    if (outbf) {
        us4 o = { f2bf(y.x), f2bf(y.y), f2bf(y.z), f2bf(y.w) };
        reinterpret_cast<us4*>(outbf + (size_t)row * D_)[t] = o;
    }
}

// ---------- launcher ----------
extern "C" void kernel_launch(void* const* d_in, const int* in_sizes, int n_in,
                              void* d_out, int out_size, void* d_ws, size_t ws_size,
                              hipStream_t stream)
{
    const float* hs   = (const float*)d_in[0];
    const float* wq   = (const float*)d_in[1];
    const float* bq   = (const float*)d_in[2];
    const float* wk   = (const float*)d_in[3];
    const float* bk   = (const float*)d_in[4];
    const float* wv   = (const float*)d_in[5];
    const float* bv   = (const float*)d_in[6];
    const float* wo   = (const float*)d_in[7];
    const float* bo   = (const float*)d_in[8];
    const float* ln1g = (const float*)d_in[9];
    const float* ln1b = (const float*)d_in[10];
    const float* fc1w = (const float*)d_in[11];
    const float* fc1b = (const float*)d_in[12];
    const float* fc2w = (const float*)d_in[13];
    const float* fc2b = (const float*)d_in[14];
    const float* ln2g = (const float*)d_in[15];
    const float* ln2b = (const float*)d_in[16];
    float* out = (float*)d_out;

    char* ws = (char*)d_ws;
    const size_t MB = 1024 * 1024;
    // liveness-packed layout, peak 184 MB
    unsigned short* hs_bf = (unsigned short*)(ws + 0);        // 16 MB
    unsigned short* wq_bf = (unsigned short*)(ws + 16 * MB);  //  2 MB
    unsigned short* wk_bf = (unsigned short*)(ws + 18 * MB);
    unsigned short* wv_bf = (unsigned short*)(ws + 20 * MB);
    unsigned short* wo_bf = (unsigned short*)(ws + 22 * MB);
    unsigned short* f1_bf = (unsigned short*)(ws + 24 * MB);  //  8 MB
    unsigned short* f2_bf = (unsigned short*)(ws + 32 * MB);  //  8 MB
    unsigned short* qbf   = (unsigned short*)(ws + 40 * MB);  // 16 MB
    unsigned short* kbf   = (unsigned short*)(ws + 56 * MB);  // 16 MB
    unsigned short* vtbf  = (unsigned short*)(ws + 72 * MB);  // 16 MB
    unsigned short* attnb = (unsigned short*)(ws + 88 * MB);  // 16 MB
    float*          tmp   = (float*)(ws + 104 * MB);          // 32 MB (reused)
    float*          ln1f  = (float*)(ws + 136 * MB);          // 32 MB
    unsigned short* ln1bf = (unsigned short*)(ws + 168 * MB); // 16 MB
    unsigned short* h_bf  = (unsigned short*)(ws + 40 * MB);  // 64 MB, aliases q/k/vt/attn (dead)

    // fp32 -> bf16 casts
    cvt_kernel<<<8192, 256, 0, stream>>>(hs,   hs_bf, 2097152);
    cvt_kernel<<<1024, 256, 0, stream>>>(wq,   wq_bf,  262144);
    cvt_kernel<<<1024, 256, 0, stream>>>(wk,   wk_bf,  262144);
    cvt_kernel<<<1024, 256, 0, stream>>>(wv,   wv_bf,  262144);
    cvt_kernel<<<1024, 256, 0, stream>>>(wo,   wo_bf,  262144);
    cvt_kernel<<<4096, 256, 0, stream>>>(fc1w, f1_bf, 1048576);
    cvt_kernel<<<4096, 256, 0, stream>>>(fc2w, f2_bf, 1048576);

    // projections
    gemm_bt<0><<<dim3(8, 64),  256, 0, stream>>>(hs_bf, wq_bf, bq, nullptr, nullptr, qbf,  SCALING_, NROWS_, D_, D_);
    gemm_bt<0><<<dim3(8, 64),  256, 0, stream>>>(hs_bf, wk_bf, bk, nullptr, nullptr, kbf,  1.0f,     NROWS_, D_, D_);
    gemm_bt<1><<<dim3(8, 64),  256, 0, stream>>>(hs_bf, wv_bf, bv, nullptr, nullptr, vtbf, 1.0f,     NROWS_, D_, D_);
    // attention
    attn_kernel<<<dim3(B_ * H_, S_ / 64), 256, 0, stream>>>(qbf, kbf, vtbf, attnb);
    // out-proj + residual
    gemm_bt<2><<<dim3(8, 64),  256, 0, stream>>>(attnb, wo_bf, bo, hs, tmp, nullptr, 1.0f, NROWS_, D_, D_);
    ln_kernel<<<NROWS_, 256, 0, stream>>>(tmp, ln1g, ln1b, ln1f, ln1bf);
    // FFN
    gemm_bt<3><<<dim3(32, 64), 256, 0, stream>>>(ln1bf, f1_bf, fc1b, nullptr, nullptr, h_bf, 1.0f, NROWS_, F_, D_);
    gemm_bt<4><<<dim3(8, 64),  256, 0, stream>>>(h_bf, f2_bf, fc2b, ln1f, tmp, nullptr, 1.0f, NROWS_, D_, F_);
    ln_kernel<<<NROWS_, 256, 0, stream>>>(tmp, ln2g, ln2b, out, nullptr);
    (void)in_sizes; (void)n_in; (void)out_size; (void)ws_size;
}

// Round 13
// 519.609 us; speedup vs baseline: 1.1229x; 1.0886x over previous
//
#include <hip/hip_runtime.h>
#include <hip/hip_bf16.h>
#include <math.h>

// Problem constants
#define B_  8
#define S_  1024
#define D_  1024
#define H_  16
#define HD_ 64
#define F_  4096
#define NROWS_ (B_*S_)          // 8192
#define SCALING_ 0.125f         // HD^-0.5
#define EPS_ 1e-5f

typedef __attribute__((ext_vector_type(8))) short bf16x8;   // 8 bf16 in 4 VGPRs (guide §3)
typedef __attribute__((ext_vector_type(4))) float f32x4;
typedef __attribute__((ext_vector_type(4))) unsigned short us4;

// ---------- helpers ----------
__device__ __forceinline__ unsigned short f2bf(float f) {
    union { float f; unsigned int u; } x; x.f = f;
    unsigned int u = x.u;
    u += 0x7FFFu + ((u >> 16) & 1u);          // round-to-nearest-even
    return (unsigned short)(u >> 16);
}

__device__ __forceinline__ unsigned int pack_bf2(float a, float b) {
    __hip_bfloat162 h = __float22bfloat162_rn(make_float2(a, b));  // v_cvt_pk_bf16_f32
    union { __hip_bfloat162 h; unsigned int u; } c; c.h = h; return c.u;
}

__device__ __forceinline__ f32x4 mfma16(bf16x8 a, bf16x8 b, f32x4 c) {
    return __builtin_amdgcn_mfma_f32_16x16x32_bf16(a, b, c, 0, 0, 0);
}

// async global->LDS, 16B per lane.  LDS dest must be WAVE-UNIFORM base
// (HW scatters lane i at base + i*16); global src is per-lane.
__device__ __forceinline__ void async_copy16(const unsigned short* g, unsigned short* l) {
    __builtin_amdgcn_global_load_lds(
        (const __attribute__((address_space(1))) void*)g,
        (__attribute__((address_space(3))) void*)l,
        16, 0, 0);
}

// swizzled LDS fragment load: tiles are [rows][64] bf16, 16B-granule XOR swizzle
// granule' = granule ^ (row&7)  (128B rows -> 8 granules -> full 3-bit XOR)
__device__ __forceinline__ bf16x8 ld_swz(const unsigned short* lds, int row, int k) {
    const int kg = (k >> 3) ^ (row & 7);
    return *reinterpret_cast<const bf16x8*>(lds + row * 64 + kg * 8);
}

// ---------- fused fp32 -> bf16 convert (all 7 tensors, one launch) ----------
// segments in float4 units (all block-aligned): hs 2097152 | wq/wk/wv/wo 262144
// each | fc1 1048576 | fc2 1048576.  total 5242880 -> 20480 blocks.
__global__ __launch_bounds__(256)
void cvt_all(const float* __restrict__ hs, const float* __restrict__ wq,
             const float* __restrict__ wk, const float* __restrict__ wv,
             const float* __restrict__ wo, const float* __restrict__ f1,
             const float* __restrict__ f2,
             unsigned short* d_hs, unsigned short* d_wq, unsigned short* d_wk,
             unsigned short* d_wv, unsigned short* d_wo, unsigned short* d_f1,
             unsigned short* d_f2)
{
    const int gid = blockIdx.x * 256 + threadIdx.x;
    const float* s; unsigned short* d; int off;
    if      (gid < 2097152) { s = hs; d = d_hs; off = gid;           }
    else if (gid < 2359296) { s = wq; d = d_wq; off = gid - 2097152; }
    else if (gid < 2621440) { s = wk; d = d_wk; off = gid - 2359296; }
    else if (gid < 2883584) { s = wv; d = d_wv; off = gid - 2621440; }
    else if (gid < 3145728) { s = wo; d = d_wo; off = gid - 2883584; }
    else if (gid < 4194304) { s = f1; d = d_f1; off = gid - 3145728; }
    else                    { s = f2; d = d_f2; off = gid - 4194304; }
    const float4 v = reinterpret_cast<const float4*>(s)[off];
    us4 o = { f2bf(v.x), f2bf(v.y), f2bf(v.z), f2bf(v.w) };
    reinterpret_cast<us4*>(d)[off] = o;
}

// ---------- GEMM C = A(MxK) * B(NxK)^T, bf16 in, fp32 acc ----------
// 128x128 tile, BK=64, 256 threads (2x2 waves of 64x64), 16x16x32 MFMA.
// 2-phase double-buffered staging (R7): STAGE(t+1) issued before compute(t),
// single barrier per K-step; implicit vmcnt(0)+lgkmcnt(0) drain at barrier.
// MODE 0: out bf16 -> [B,H,S,HD] (q/k layout), val=(acc+bias)*scale
// MODE 1: out bf16 -> [B,H,HD,S] (v transposed layout)
// MODE 2: out f32  -> acc+bias+resid (row-major MxN)
// MODE 3: out bf16 -> gelu_tanh(acc+bias) (row-major MxN)
// MODE 4: same as 2
template<int MODE>
__global__ __launch_bounds__(256)
void gemm_bt(const unsigned short* __restrict__ A,
             const unsigned short* __restrict__ Bw,
             const float* __restrict__ bias,
             const float* __restrict__ resid,
             float* __restrict__ outf,
             unsigned short* __restrict__ outb,
             float scale, int M, int N, int K)
{
    alignas(16) __shared__ unsigned short lA[2][128 * 64];   // dbuf, 32 KB each pair
    alignas(16) __shared__ unsigned short lB[2][128 * 64];
    const int tid  = threadIdx.x;
    const int lane = tid & 63, wave = tid >> 6;
    const int wr = wave >> 1, wc = wave & 1;
    const int l15 = lane & 15, lg = lane >> 4;
    const int brow = blockIdx.y * 128, bcol = blockIdx.x * 128;

    f32x4 acc[4][4];
#pragma unroll
    for (int m = 0; m < 4; ++m)
#pragma unroll
        for (int n = 0; n < 4; ++n) acc[m][n] = f32x4{0.f, 0.f, 0.f, 0.f};

    // stage 128x64 bf16 tiles of A and B (16KB each) into buffer `buf`,
    // linear LDS dest, inverse-swizzled global source (rule #21)
#define GSTAGE(buf, k0)                                                            \
    {                                                                              \
        _Pragma("unroll")                                                          \
        for (int j = 0; j < 4; ++j) {                                              \
            const int c   = wave * 4 + j;       /* 1KB chunk id 0..15 */           \
            const int p   = c * 64 + lane;      /* 16B granule 0..1023 */          \
            const int row = p >> 3;                                                \
            const int kg  = (p & 7) ^ (row & 7);                                   \
            async_copy16(&A [(size_t)(brow + row) * K + (k0) + kg * 8], &lA[buf][c * 512]); \
            async_copy16(&Bw[(size_t)(bcol + row) * K + (k0) + kg * 8], &lB[buf][c * 512]); \
        }                                                                          \
    }

    GSTAGE(0, 0);                         // prologue prefetch
    const int nk = K >> 6;
    for (int t = 0; t < nk; ++t) {
        const int cur = t & 1;
        __syncthreads();                  // drains vmcnt(0): tile t landed; all
                                          // waves done reading buf cur^1
        if (t + 1 < nk) GSTAGE(cur ^ 1, (t + 1) * 64);   // flies under compute(t)
#pragma unroll
        for (int kk = 0; kk < 2; ++kk) {
            bf16x8 af[4], bfr[4];
#pragma unroll
            for (int m = 0; m < 4; ++m) af[m]  = ld_swz(lA[cur], wr * 64 + m * 16 + l15, kk * 32 + lg * 8);
#pragma unroll
            for (int n = 0; n < 4; ++n) bfr[n] = ld_swz(lB[cur], wc * 64 + n * 16 + l15, kk * 32 + lg * 8);
#pragma unroll
            for (int m = 0; m < 4; ++m)
#pragma unroll
                for (int n = 0; n < 4; ++n)
                    acc[m][n] = mfma16(af[m], bfr[n], acc[m][n]);
        }
    }
#undef GSTAGE

    // epilogue.  C/D layout: col = lane&15, row = (lane>>4)*4 + r  (guide §3, m89-verified)
#pragma unroll
    for (int m = 0; m < 4; ++m) {
#pragma unroll
        for (int n = 0; n < 4; ++n) {
#pragma unroll
            for (int r = 0; r < 4; ++r) {
                const int grow = brow + wr * 64 + m * 16 + lg * 4 + r;
                const int gcol = bcol + wc * 64 + n * 16 + l15;
                float v = acc[m][n][r] + bias[gcol];
                if constexpr (MODE == 0) {
                    v *= scale;
                    const int b = grow >> 10, s = grow & 1023, h = gcol >> 6, hd = gcol & 63;
                    outb[(((size_t)b * H_ + h) * S_ + s) * HD_ + hd] = f2bf(v);
                } else if constexpr (MODE == 1) {
                    const int b = grow >> 10, s = grow & 1023, h = gcol >> 6, hd = gcol & 63;
                    outb[(((size_t)b * H_ + h) * HD_ + hd) * S_ + s] = f2bf(v);
                } else if constexpr (MODE == 2 || MODE == 4) {
                    outf[(size_t)grow * N + gcol] = v + resid[(size_t)grow * N + gcol];
                } else {
                    // MODE 3: tanh-approx GELU (|err| < 1e-3 vs exact erf form);
                    // tanh(z) = 1 - 2/(e^{2z}+1), saturates correctly at +/-inf
                    const float z  = v * (0.7978845608028654f + 0.035677408136300125f * v * v);
                    const float e  = __expf(2.0f * z);
                    const float th = 1.0f - 2.0f / (e + 1.0f);
                    const float g  = 0.5f * v * (1.0f + th);
                    outb[(size_t)grow * N + gcol] = f2bf(g);
                }
            }
        }
    }
}

// ---------- flash attention (swapped-operand, validated R6) ----------
// grid (B*H, S/64).  256 threads = 4 waves, each wave owns 16 query rows.
// Computes S^T = mfma(K,Q) so each lane holds 16 scores for ONE query
// (lane-local softmax), and O^T = mfma(V^T, P^T).
// q,k: [B,H,S,64] bf16 (q pre-scaled).  vt: [B,H,64,S] bf16.
// out: attn [B,S,D] bf16.
__global__ __launch_bounds__(256)
void attn_kernel(const unsigned short* __restrict__ qb,
                 const unsigned short* __restrict__ kb,
                 const unsigned short* __restrict__ vtb,
                 unsigned short* __restrict__ attn)
{
    alignas(16) __shared__ unsigned short lK[2][64 * 64];   // dbuf K tile [key][d]
    alignas(16) __shared__ unsigned short lV[2][64 * 64];   // dbuf Vt tile [d][key]
    alignas(16) __shared__ unsigned short lP[4][16 * 72];   // per-wave P[query][key], +8 pad
    const int bh = blockIdx.x, qblk = blockIdx.y;
    const int tid = threadIdx.x, lane = tid & 63, wave = tid >> 6;
    const int l15 = lane & 15, lg = lane >> 4;
    const int b = bh >> 4, h = bh & 15;

    const unsigned short* Kg = kb  + (size_t)bh * S_ * HD_;
    const unsigned short* Vg = vtb + (size_t)bh * HD_ * S_;
    const unsigned short* Qg = qb  + ((size_t)bh * S_ + qblk * 64 + wave * 16) * HD_;

    // Q fragment as MFMA B-operand: col=query=l15, k=d=lg*8 (+32)
    bf16x8 qf0 = *reinterpret_cast<const bf16x8*>(Qg + l15 * HD_ + lg * 8);
    bf16x8 qf1 = *reinterpret_cast<const bf16x8*>(Qg + l15 * HD_ + lg * 8 + 32);

    float mr = -1e30f, lr = 0.f;     // lane-local: running max/denominator for query l15
    f32x4 o[4];                      // O^T fragments: d = m*16+lg*4+r, query = l15
#pragma unroll
    for (int m = 0; m < 4; ++m) o[m] = f32x4{0.f, 0.f, 0.f, 0.f};

    // staging helper: tile t -> buffer buf
#define STAGE(buf, t)                                                              \
    {                                                                              \
        _Pragma("unroll")                                                          \
        for (int j = 0; j < 2; ++j) {                                              \
            const int c   = wave * 2 + j;       /* 1KB chunk 0..7 */               \
            const int p   = c * 64 + lane;      /* 16B granule 0..511 */           \
            const int row = p >> 3;                                                \
            const int kg  = (p & 7) ^ (row & 7);                                   \
            async_copy16(&Kg[(size_t)((t) * 64 + row) * HD_ + kg * 8], &lK[buf][c * 512]); \
            async_copy16(&Vg[(size_t)row * S_ + (t) * 64 + kg * 8],    &lV[buf][c * 512]); \
        }                                                                          \
    }

    STAGE(0, 0);                      // prologue prefetch

    unsigned short* Pl = &lP[wave][0];

    for (int t = 0; t < 16; ++t) {
        const int cur = t & 1;
        __syncthreads();              // drains vmcnt(0): tile t landed; all waves left buf cur^1
        if (t < 15) STAGE(cur ^ 1, t + 1);   // prefetch flies under compute(t)

        // S^T = K Q^T : fragment n -> key = n*16 + lg*4 + r, query = l15
        f32x4 sf[4];
#pragma unroll
        for (int n = 0; n < 4; ++n) {
            f32x4 z = {0.f, 0.f, 0.f, 0.f};
            z     = mfma16(ld_swz(lK[cur], n * 16 + l15, lg * 8),      qf0, z);
            sf[n] = mfma16(ld_swz(lK[cur], n * 16 + l15, 32 + lg * 8), qf1, z);
        }

        // lane-local online softmax (16 in-lane keys + 2 butterfly rounds over lane-groups)
        float tmax = sf[0][0];
#pragma unroll
        for (int n = 0; n < 4; ++n)
#pragma unroll
            for (int r = 0; r < 4; ++r) tmax = fmaxf(tmax, sf[n][r]);
        tmax = fmaxf(tmax, __shfl_xor(tmax, 16, 64));
        tmax = fmaxf(tmax, __shfl_xor(tmax, 32, 64));
        const float mnew = fmaxf(mr, tmax);
        const float corr = __expf(mr - mnew);
        mr = mnew;

        float ps = 0.f;
        uint2 pk[4];                  // packed bf16 P: keys n*16+lg*4+{0..3}, query l15
#pragma unroll
        for (int n = 0; n < 4; ++n) {
            float p0 = __expf(sf[n][0] - mr);
            float p1 = __expf(sf[n][1] - mr);
            float p2 = __expf(sf[n][2] - mr);
            float p3 = __expf(sf[n][3] - mr);
            ps += (p0 + p1) + (p2 + p3);
            pk[n].x = pack_bf2(p0, p1);
            pk[n].y = pack_bf2(p2, p3);
        }
        ps += __shfl_xor(ps, 16, 64);
        ps += __shfl_xor(ps, 32, 64);
        lr = lr * corr + ps;
#pragma unroll
        for (int m = 0; m < 4; ++m)
#pragma unroll
            for (int r = 0; r < 4; ++r) o[m][r] *= corr;

        // P (transposed to [query][key]) -> per-wave LDS tile, 4x ds_write_b64
#pragma unroll
        for (int n = 0; n < 4; ++n)
            *reinterpret_cast<uint2*>(Pl + l15 * 72 + n * 16 + lg * 4) = pk[n];

        // O^T += V^T * P^T : A = Vt rows (d), B = P^T (col=query, k=key)
#pragma unroll
        for (int kk = 0; kk < 2; ++kk) {
            bf16x8 pf = *reinterpret_cast<const bf16x8*>(Pl + l15 * 72 + kk * 32 + lg * 8);
#pragma unroll
            for (int m = 0; m < 4; ++m)
                o[m] = mfma16(ld_swz(lV[cur], m * 16 + l15, kk * 32 + lg * 8), pf, o[m]);
        }
    }
#undef STAGE

    // write attn[b, s=query, h*64 + d], 8B packed stores (4 consecutive d)
    const int s = qblk * 64 + wave * 16 + l15;
    const float rinv = 1.0f / lr;
#pragma unroll
    for (int m = 0; m < 4; ++m) {
        us4 w = { f2bf(o[m][0] * rinv), f2bf(o[m][1] * rinv),
                  f2bf(o[m][2] * rinv), f2bf(o[m][3] * rinv) };
        *reinterpret_cast<us4*>(attn + ((size_t)b * S_ + s) * D_ + h * HD_ + m * 16 + lg * 4) = w;
    }
}

// ---------- row LayerNorm over D=1024, one block per row ----------
__global__ __launch_bounds__(256)
void ln_kernel(const float* __restrict__ in, const float* __restrict__ gam,
               const float* __restrict__ bet,
               float* __restrict__ outf, unsigned short* __restrict__ outbf)
{
    const int row = blockIdx.x, t = threadIdx.x;
    const float4 v = reinterpret_cast<const float4*>(in + (size_t)row * D_)[t];
    float s  = v.x + v.y + v.z + v.w;
    float s2 = v.x * v.x + v.y * v.y + v.z * v.z + v.w * v.w;
#pragma unroll
    for (int off = 32; off > 0; off >>= 1) {
        s  += __shfl_down(s, off, 64);
        s2 += __shfl_down(s2, off, 64);
    }
    __shared__ float red[2][4];
    if ((t & 63) == 0) { red[0][t >> 6] = s; red[1][t >> 6] = s2; }
    __syncthreads();
    s  = red[0][0] + red[0][1] + red[0][2] + red[0][3];
    s2 = red[1][0] + red[1][1] + red[1][2] + red[1][3];
    const float mean = s * (1.0f / D_);
    const float rstd = rsqrtf(s2 * (1.0f / D_) - mean * mean + EPS_);
    const float4 g4 = reinterpret_cast<const float4*>(gam)[t];
    const float4 b4 = reinterpret_cast<const float4*>(bet)[t];
    float4 y;
    y.x = (v.x - mean) * rstd * g4.x + b4.x;
    y.y = (v.y - mean) * rstd * g4.y + b4.y;
    y.z = (v.z - mean) * rstd * g4.z + b4.z;
    y.w = (v.w - mean) * rstd * g4.w + b4.w;
    if (outf)  reinterpret_cast<float4*>(outf + (size_t)row * D_)[t] = y;
    if (outbf) {
        us4 o = { f2bf(y.x), f2bf(y.y), f2bf(y.z), f2bf(y.w) };
        reinterpret_cast<us4*>(outbf + (size_t)row * D_)[t] = o;
    }
}

// ---------- launcher ----------
extern "C" void kernel_launch(void* const* d_in, const int* in_sizes, int n_in,
                              void* d_out, int out_size, void* d_ws, size_t ws_size,
                              hipStream_t stream)
{
    const float* hs   = (const float*)d_in[0];
    const float* wq   = (const float*)d_in[1];
    const float* bq   = (const float*)d_in[2];
    const float* wk   = (const float*)d_in[3];
    const float* bk   = (const float*)d_in[4];
    const float* wv   = (const float*)d_in[5];
    const float* bv   = (const float*)d_in[6];
    const float* wo   = (const float*)d_in[7];
    const float* bo   = (const float*)d_in[8];
    const float* ln1g = (const float*)d_in[9];
    const float* ln1b = (const float*)d_in[10];
    const float* fc1w = (const float*)d_in[11];
    const float* fc1b = (const float*)d_in[12];
    const float* fc2w = (const float*)d_in[13];
    const float* fc2b = (const float*)d_in[14];
    const float* ln2g = (const float*)d_in[15];
    const float* ln2b = (const float*)d_in[16];
    float* out = (float*)d_out;

    char* ws = (char*)d_ws;
    const size_t MB = 1024 * 1024;
    // liveness-packed layout, peak 184 MB
    unsigned short* hs_bf = (unsigned short*)(ws + 0);        // 16 MB
    unsigned short* wq_bf = (unsigned short*)(ws + 16 * MB);  //  2 MB
    unsigned short* wk_bf = (unsigned short*)(ws + 18 * MB);
    unsigned short* wv_bf = (unsigned short*)(ws + 20 * MB);
    unsigned short* wo_bf = (unsigned short*)(ws + 22 * MB);
    unsigned short* f1_bf = (unsigned short*)(ws + 24 * MB);  //  8 MB
    unsigned short* f2_bf = (unsigned short*)(ws + 32 * MB);  //  8 MB
    unsigned short* qbf   = (unsigned short*)(ws + 40 * MB);  // 16 MB
    unsigned short* kbf   = (unsigned short*)(ws + 56 * MB);  // 16 MB
    unsigned short* vtbf  = (unsigned short*)(ws + 72 * MB);  // 16 MB
    unsigned short* attnb = (unsigned short*)(ws + 88 * MB);  // 16 MB
    float*          tmp   = (float*)(ws + 104 * MB);          // 32 MB (reused)
    float*          ln1f  = (float*)(ws + 136 * MB);          // 32 MB
    unsigned short* ln1bf = (unsigned short*)(ws + 168 * MB); // 16 MB
    unsigned short* h_bf  = (unsigned short*)(ws + 40 * MB);  // 64 MB, aliases q/k/vt/attn (dead)

    // fp32 -> bf16 casts, single fused launch (20480 blocks)
    cvt_all<<<20480, 256, 0, stream>>>(hs, wq, wk, wv, wo, fc1w, fc2w,
                                       hs_bf, wq_bf, wk_bf, wv_bf, wo_bf, f1_bf, f2_bf);

    // projections
    gemm_bt<0><<<dim3(8, 64),  256, 0, stream>>>(hs_bf, wq_bf, bq, nullptr, nullptr, qbf,  SCALING_, NROWS_, D_, D_);
    gemm_bt<0><<<dim3(8, 64),  256, 0, stream>>>(hs_bf, wk_bf, bk, nullptr, nullptr, kbf,  1.0f,     NROWS_, D_, D_);
    gemm_bt<1><<<dim3(8, 64),  256, 0, stream>>>(hs_bf, wv_bf, bv, nullptr, nullptr, vtbf, 1.0f,     NROWS_, D_, D_);
    // attention
    attn_kernel<<<dim3(B_ * H_, S_ / 64), 256, 0, stream>>>(qbf, kbf, vtbf, attnb);
    // out-proj + residual
    gemm_bt<2><<<dim3(8, 64),  256, 0, stream>>>(attnb, wo_bf, bo, hs, tmp, nullptr, 1.0f, NROWS_, D_, D_);
    ln_kernel<<<NROWS_, 256, 0, stream>>>(tmp, ln1g, ln1b, ln1f, ln1bf);
    // FFN
    gemm_bt<3><<<dim3(32, 64), 256, 0, stream>>>(ln1bf, f1_bf, fc1b, nullptr, nullptr, h_bf, 1.0f, NROWS_, F_, D_);
    gemm_bt<4><<<dim3(8, 64),  256, 0, stream>>>(h_bf, f2_bf, fc2b, ln1f, tmp, nullptr, 1.0f, NROWS_, D_, F_);
    ln_kernel<<<NROWS_, 256, 0, stream>>>(tmp, ln2g, ln2b, out, nullptr);
    (void)in_sizes; (void)n_in; (void)out_size; (void)ws_size;
}